// Round 9
// baseline (733.536 us; speedup 1.0000x reference)
//
#include <hip/hip_runtime.h>
#include <math.h>

#define M_SEQ 11520   // B*N
#define NNODE 360
#define NB    32
#define TT    64
#define DTH   192     // decode threads: 3 waves, 2 nodes/lane (n, n+192)

// GRU/feat/adj path: libm-accurate (feeds the precision-fragile argmax;
// __expf there = ~25% chance of a full-scale argmax flip — do not).
__device__ __forceinline__ float fsig(float x)  { return 1.0f / (1.0f + expf(-x)); }
__device__ __forceinline__ float ftanh(float x) { return tanhf(x); }
// Decode path: post-argmax, fast hardware exp. Drift budget ~4e-5, measured 3.8e-6.
__device__ __forceinline__ float fsigd(float x)  { return 1.0f / (1.0f + __expf(-x)); }
__device__ __forceinline__ float ftanhd(float x) { return 1.0f - 2.0f / (__expf(2.0f * x) + 1.0f); }

// ---------------- JAX threefry2x32, key=(0,42), partitionable, bits=y0^y1 ----
__device__ __forceinline__ unsigned rotl32(unsigned x, int n) { return (x << n) | (x >> (32 - n)); }

__device__ __forceinline__ void tf2x32(unsigned& x0, unsigned& x1)
{
    const unsigned k0 = 0u, k1 = 42u, k2 = 0u ^ 42u ^ 0x1BD11BDAu;
    x0 += k0; x1 += k1;
#define R4(a,b,c,d) \
    x0 += x1; x1 = rotl32(x1,a); x1 ^= x0; \
    x0 += x1; x1 = rotl32(x1,b); x1 ^= x0; \
    x0 += x1; x1 = rotl32(x1,c); x1 ^= x0; \
    x0 += x1; x1 = rotl32(x1,d); x1 ^= x0;
    R4(13,15,26,6)   x0 += k1; x1 += k2 + 1u;
    R4(17,29,16,24)  x0 += k2; x1 += k0 + 2u;
    R4(13,15,26,6)   x0 += k0; x1 += k1 + 3u;
    R4(17,29,16,24)  x0 += k1; x1 += k2 + 4u;
    R4(13,15,26,6)   x0 += k2; x1 += k0 + 5u;
#undef R4
}

__device__ __forceinline__ float jax_uniform(unsigned idx)
{
    unsigned x0 = 0u, x1 = idx;
    tf2x32(x0, x1);
    unsigned bits = x0 ^ x1;          // VERIFIED R5
    return __uint_as_float((bits >> 9) | 0x3f800000u) - 1.0f;
}

// broadcast within aligned 8-lane group via static-pattern ds_swizzle:
// BitMode offset = (xor<<10)|(or<<5)|and; src = (lane & 0x18) | K.
// K must be a compile-time constant -> template-parameter unroll.
template<int K>
__device__ __forceinline__ void swz_fma(float h, const float* w0, const float* w1,
                                        const float* w2, float& g0, float& g1, float& g2)
{
    float hk = __int_as_float(
        __builtin_amdgcn_ds_swizzle(__float_as_int(h), (K << 5) | 0x18));
    g0 += hk * w0[K];
    g1 += hk * w1[K];
    g2 += hk * w2[K];
    if constexpr (K < 7)
        swz_fma<K + 1>(h, w0, w1, w2, g0, g1, g2);
}

// ---------------- fused bidirectional GRU layer -----------------------------
template<int I>
__global__ __launch_bounds__(256) void gru_fused(
    const float* __restrict__ x,    // (M,64,I)
    const float* __restrict__ wih,  // (2,24,I)
    const float* __restrict__ whh,  // (2,24,8)
    const float* __restrict__ bih,  // (2,24)
    const float* __restrict__ bhh,  // (2,24)
    float* __restrict__ out)        // (M,64,16), dir writes its 8-half
{
    const int tid = blockIdx.x * 256 + threadIdx.x;
    const int j   = tid & 7;
    const int md  = tid >> 3;
    if (md >= M_SEQ * 2) return;
    const int m = md >> 1, dir = md & 1;

    float wx0[I], wx1[I], wx2[I];
    const float* WI = wih + dir * 24 * I;
#pragma unroll
    for (int k = 0; k < I; ++k) {
        wx0[k] = WI[j * I + k];
        wx1[k] = WI[(8 + j) * I + k];
        wx2[k] = WI[(16 + j) * I + k];
    }
    float w0[8], w1[8], w2[8];
    const float* WH = whh + dir * 192;
#pragma unroll
    for (int k = 0; k < 8; ++k) {
        w0[k] = WH[j * 8 + k];
        w1[k] = WH[(8 + j) * 8 + k];
        w2[k] = WH[(16 + j) * 8 + k];
    }
    const float bx0 = bih[dir*24 + j], bx1 = bih[dir*24 + 8 + j], bx2 = bih[dir*24 + 16 + j];
    const float bh0 = bhh[dir*24 + j], bh1 = bhh[dir*24 + 8 + j], bh2 = bhh[dir*24 + 16 + j];

    const float* xm = x + (size_t)m * TT * I;
    float* om = out + (size_t)m * TT * 16 + dir * 8 + j;

    float h = 0.f;
    for (int tt = 0; tt < TT; ++tt) {
        const int t = dir ? (TT - 1 - tt) : tt;
        float xv[I];
        const float4* xp4 = reinterpret_cast<const float4*>(xm + t * I);
#pragma unroll
        for (int q = 0; q < I / 4; ++q) {
            float4 f = xp4[q];
            xv[4*q] = f.x; xv[4*q+1] = f.y; xv[4*q+2] = f.z; xv[4*q+3] = f.w;
        }
        float xr = bx0, xz = bx1, xn = bx2;
#pragma unroll
        for (int k = 0; k < I; ++k) {
            xr += xv[k] * wx0[k];
            xz += xv[k] * wx1[k];
            xn += xv[k] * wx2[k];
        }
        float gh0 = bh0, gh1 = bh1, gh2 = bh2;
        swz_fma<0>(h, w0, w1, w2, gh0, gh1, gh2);   // 8 static-pattern swizzles
        float r  = fsig(xr + gh0);
        float z  = fsig(xz + gh1);
        float nn = ftanh(xn + r * gh2);
        h = (1.f - z) * nn + z * h;
        om[t * 16] = h;
    }
}

// ---------------- feat MLP ---------------------------------------------------
__global__ void feat_kernel(const float* __restrict__ gout,
                            const float* __restrict__ l1w, const float* __restrict__ l1b,
                            const float* __restrict__ l2w, const float* __restrict__ l2b,
                            float* __restrict__ feat)
{
    int m = blockIdx.x * blockDim.x + threadIdx.x;
    if (m >= M_SEQ) return;
    const float* xp = gout + (size_t)m * TT * 16 + (TT - 1) * 16;
    float xv[16];
#pragma unroll
    for (int i = 0; i < 16; ++i) xv[i] = xp[i];
    float h1[8];
#pragma unroll
    for (int o = 0; o < 8; ++o) {
        float a = 0.f;
#pragma unroll
        for (int f = 0; f < 16; ++f) a += xv[f] * l1w[o * 16 + f];
        a += l1b[o];
        h1[o] = (a >= 0.f) ? a : 0.2f * a;
    }
#pragma unroll
    for (int o = 0; o < 8; ++o) {
        float a = 0.f;
#pragma unroll
        for (int f = 0; f < 8; ++f) a += h1[f] * l2w[o * 8 + f];
        feat[(size_t)m * 8 + o] = a + l2b[o];
    }
}

// ---------------- adjacency: per row -> (argmax col, adj value v) -----------
__global__ void adj_kernel(const float* __restrict__ feat,
                           const float* __restrict__ tptr,
                           int* __restrict__ colp, float* __restrict__ vp)
{
    const int gw   = (blockIdx.x * blockDim.x + threadIdx.x) >> 6;
    const int lane = threadIdx.x & 63;
    if (gw >= NB * NNODE) return;
    const int b = gw / NNODE;
    const int n = gw - b * NNODE;
    const float T = tptr[0];
    const float* fb = feat + (size_t)b * NNODE * 8;
    float fn[8];
#pragma unroll
    for (int k = 0; k < 8; ++k) fn[k] = fb[(size_t)n * 8 + k];

    float sv[6];
    float mval = -3.0e38f; int midx = 1 << 30;
#pragma unroll
    for (int s = 0; s < 6; ++s) {
        int p = s * 64 + lane;
        float xs = -3.0e38f;
        if (p < NNODE) {
            const float* fp = fb + (size_t)p * 8;
            float d = 0.f;
#pragma unroll
            for (int k = 0; k < 8; ++k) d += fn[k] * fp[k];
            unsigned idx = (unsigned)gw * 360u + (unsigned)p;
            float u   = jax_uniform(idx);
            float gum = -logf(-logf(u + 1e-10f) + 1e-10f);
            xs = (d + gum) / T;
            if (xs > mval) { mval = xs; midx = p; }
        }
        sv[s] = xs;
    }
    for (int off = 32; off > 0; off >>= 1) {   // ties -> smaller index
        float ov = __shfl_xor(mval, off);
        int   oi = __shfl_xor(midx, off);
        if (ov > mval || (ov == mval && oi < midx)) { mval = ov; midx = oi; }
    }
    float ssum = 0.f;
#pragma unroll
    for (int s = 0; s < 6; ++s) {
        int p = s * 64 + lane;
        if (p < NNODE) ssum += expf(sv[s] - mval);
    }
    for (int off = 32; off > 0; off >>= 1) ssum += __shfl_xor(ssum, off);
    if (lane == 0) {
        float ys = 1.0f / ssum;
        float v  = ys + (1.0f - ys);
        if (midx == n) v = 0.0f;
        colp[gw] = midx;
        vp[gw]   = v;
    }
}

// ---------------- DCGRU: one node's layer-phase math -------------------------
// Gathers along the functional-graph chain cc[0..4]; redundant r at c1,c2
// (identical formula to owning threads -> numerically equal, no rh barrier).
__device__ __forceinline__ float dc_node(
    const float* so_l, const float* sh_lp,
    const float* W, float bgr, float bgu, const float* C, float cb,
    const int* cc, const float* vL, const float* wv)
{
    float o0 = so_l[cc[0]], o1 = so_l[cc[1]], o2 = so_l[cc[2]],
          o3 = so_l[cc[3]], o4 = so_l[cc[4]];
    float h0 = sh_lp[cc[0]], h1 = sh_lp[cc[1]], h2 = sh_lp[cc[2]],
          h3g = sh_lp[cc[3]], h4 = sh_lp[cc[4]];
    float f1 = vL[0]*o1, f2 = wv[0]*o2 - o0, f4 = vL[0]*h1, f5 = wv[0]*h2 - h0;
    float r0 = fsigd(o0*W[0] + f1*W[2] + f2*W[4] + h0*W[6] + f4*W[8] + f5*W[10] + bgr);
    float u0 = fsigd(o0*W[1] + f1*W[3] + f2*W[5] + h0*W[7] + f4*W[9] + f5*W[11] + bgu);
    float a1 = vL[1]*o2, b1 = wv[1]*o3 - o1, c1f = vL[1]*h2, d1 = wv[1]*h3g - h1;
    float r1 = fsigd(o1*W[0] + a1*W[2] + b1*W[4] + h1*W[6] + c1f*W[8] + d1*W[10] + bgr);
    float a2 = vL[2]*o3, b2 = wv[2]*o4 - o2, c2f = vL[2]*h3g, d2 = wv[2]*h4 - h2;
    float r2 = fsigd(o2*W[0] + a2*W[2] + b2*W[4] + h2*W[6] + c2f*W[8] + d2*W[10] + bgr);
    float rh0 = r0 * h0, rh1 = r1 * h1, rh2 = r2 * h2;
    float cnd = ftanhd(o0*C[0] + f1*C[1] + f2*C[2]
                       + rh0*C[3] + (vL[0]*rh1)*C[4] + (wv[0]*rh2 - rh0)*C[5] + cb);
    return u0 * h0 + (1.f - u0) * cnd;
}

// 3-layer step for TWO nodes per lane (n, n+DTH). 3 barriers/step.
__device__ __forceinline__ void dc_step3_dual(
    float (*s_o)[NNODE], float (*s_h)[2][NNODE], int p,
    const float* Wg, const float* Bg, const float* Wc, const float* Cb,
    bool act1, int n0, int n1,
    const int cc[2][5], const float vL[2][3], const float wv[2][3],
    float& h3a, float& h3b)
{
    for (int l = 0; l < 3; ++l) {
        __syncthreads();   // o[l] / h[l][p] ready
        const float* W = Wg + l * 12;
        const float* C = Wc + l * 6;
        const float bgr = Bg[l * 2], bgu = Bg[l * 2 + 1], cb = Cb[l];
        float ha = dc_node(s_o[l], s_h[l][p], W, bgr, bgu, C, cb, cc[0], vL[0], wv[0]);
        float hb = 0.f;
        if (act1) hb = dc_node(s_o[l], s_h[l][p], W, bgr, bgu, C, cb, cc[1], vL[1], wv[1]);
        s_h[l][p ^ 1][n0] = ha; if (l < 2) s_o[l + 1][n0] = ha;
        if (act1) { s_h[l][p ^ 1][n1] = hb; if (l < 2) s_o[l + 1][n1] = hb; }
        h3a = ha; h3b = hb;
    }
}

__global__ __launch_bounds__(DTH) void decode_kernel(
    const float* __restrict__ rec,   // (B, N, T)
    const int*   __restrict__ colp, const float* __restrict__ vp,
    const float* __restrict__ egw, const float* __restrict__ egb,
    const float* __restrict__ ecw, const float* __restrict__ ecb,
    const float* __restrict__ dgw, const float* __restrict__ dgb,
    const float* __restrict__ dcw, const float* __restrict__ dcb,
    const float* __restrict__ pw,  const float* __restrict__ pb,
    float* __restrict__ outp)        // (B, N, T)
{
    __shared__ float s_o[3][NNODE];
    __shared__ float s_h[3][2][NNODE];
    __shared__ float s_v[NNODE];
    __shared__ int   s_c[NNODE];
    __shared__ float s_egw[36], s_egb[6], s_ecw[18], s_ecb[3];
    __shared__ float s_dgw[36], s_dgb[6], s_dcw[18], s_dcb[3];

    const int b = blockIdx.x;
    const int tid = threadIdx.x;
    if (tid < 36) { s_egw[tid] = egw[tid]; s_dgw[tid] = dgw[tid]; }
    if (tid < 6)  { s_egb[tid] = egb[tid]; s_dgb[tid] = dgb[tid]; }
    if (tid < 18) { s_ecw[tid] = ecw[tid]; s_dcw[tid] = dcw[tid]; }
    if (tid < 3)  { s_ecb[tid] = ecb[tid]; s_dcb[tid] = dcb[tid]; }
    const int n0 = tid, n1 = tid + DTH;
    const bool act1 = n1 < NNODE;   // DTH=192: nodes 192..359 on lanes 0..167
    {
        s_c[n0] = colp[b * NNODE + n0];
        s_v[n0] = vp[b * NNODE + n0];
        s_h[0][0][n0] = 0.f; s_h[1][0][n0] = 0.f; s_h[2][0][n0] = 0.f;
        if (act1) {
            s_c[n1] = colp[b * NNODE + n1];
            s_v[n1] = vp[b * NNODE + n1];
            s_h[0][0][n1] = 0.f; s_h[1][0][n1] = 0.f; s_h[2][0][n1] = 0.f;
        }
    }
    __syncthreads();
    int   cc[2][5] = {{0,0,0,0,0},{0,0,0,0,0}};
    float vL[2][3] = {{0,0,0},{0,0,0}}, wv[2][3] = {{0,0,0},{0,0,0}};
#pragma unroll
    for (int q = 0; q < 2; ++q) {
        if (q == 1 && !act1) break;
        int nn = q ? n1 : n0;
        cc[q][0] = nn; cc[q][1] = s_c[cc[q][0]]; cc[q][2] = s_c[cc[q][1]];
        cc[q][3] = s_c[cc[q][2]]; cc[q][4] = s_c[cc[q][3]];
        float v0 = s_v[cc[q][0]], v1 = s_v[cc[q][1]], v2 = s_v[cc[q][2]], v3 = s_v[cc[q][3]];
        vL[q][0] = v0; vL[q][1] = v1; vL[q][2] = v2;
        wv[q][0] = 2.f*v0*v1; wv[q][1] = 2.f*v1*v2; wv[q][2] = 2.f*v2*v3;
    }
    const float projw = pw[0], projb = pb[0];
    int p = 0;
    float h3a, h3b;

    // encoder (prefetch next step's strided reads)
    float in0 = rec[((size_t)b * NNODE + n0) * TT + 0];
    float in1 = act1 ? rec[((size_t)b * NNODE + n1) * TT + 0] : 0.f;
    for (int t = 0; t < TT; ++t) {
        float nx0 = (t + 1 < TT) ? rec[((size_t)b * NNODE + n0) * TT + t + 1] : 0.f;
        float nx1 = (act1 && t + 1 < TT) ? rec[((size_t)b * NNODE + n1) * TT + t + 1] : 0.f;
        s_o[0][n0] = in0;
        if (act1) s_o[0][n1] = in1;
        dc_step3_dual(s_o, s_h, p, s_egw, s_egb, s_ecw, s_ecb,
                      act1, n0, n1, cc, vL, wv, h3a, h3b);
        p ^= 1;
        in0 = nx0; in1 = nx1;
    }
    // decoder (feedback = proj)
    float d0 = 0.f, d1 = 0.f;
    for (int t = 0; t < TT; ++t) {
        s_o[0][n0] = d0;
        if (act1) s_o[0][n1] = d1;
        dc_step3_dual(s_o, s_h, p, s_dgw, s_dgb, s_dcw, s_dcb,
                      act1, n0, n1, cc, vL, wv, h3a, h3b);
        p ^= 1;
        float p0 = h3a * projw + projb;
        float p1 = h3b * projw + projb;
        outp[((size_t)b * NNODE + n0) * TT + t] = p0;
        if (act1) outp[((size_t)b * NNODE + n1) * TT + t] = p1;
        d0 = p0; d1 = p1;
    }
}

// ---------------- host launcher ---------------------------------------------
extern "C" void kernel_launch(void* const* d_in, const int* in_sizes, int n_in,
                              void* d_out, int out_size, void* d_ws, size_t ws_size,
                              hipStream_t stream)
{
    (void)in_sizes; (void)n_in; (void)out_size; (void)ws_size;
    const float* full_seq = (const float*)d_in[0];   // (M,64,8)
    const float* rec_seq  = (const float*)d_in[1];   // (32,360,64)
    const float* temp     = (const float*)d_in[3];
    const float* g0wih    = (const float*)d_in[4];
    const float* g0whh    = (const float*)d_in[5];
    const float* g0bih    = (const float*)d_in[6];
    const float* g0bhh    = (const float*)d_in[7];
    const float* gwih     = (const float*)d_in[8];   // (3,2,24,16)
    const float* gwhh     = (const float*)d_in[9];   // (3,2,24,8)
    const float* gbih     = (const float*)d_in[10];
    const float* gbhh     = (const float*)d_in[11];
    const float* l1w      = (const float*)d_in[12];
    const float* l1b      = (const float*)d_in[13];
    const float* l2w      = (const float*)d_in[14];
    const float* l2b      = (const float*)d_in[15];
    const float* enc_gw   = (const float*)d_in[16];
    const float* enc_gb   = (const float*)d_in[17];
    const float* enc_cw   = (const float*)d_in[18];
    const float* enc_cb   = (const float*)d_in[19];
    const float* dec_gw   = (const float*)d_in[20];
    const float* dec_gb   = (const float*)d_in[21];
    const float* dec_cw   = (const float*)d_in[22];
    const float* dec_cb   = (const float*)d_in[23];
    const float* proj_w   = (const float*)d_in[24];
    const float* proj_b   = (const float*)d_in[25];
    float* outp = (float*)d_out;

    // ws: small-first; bufA+bufB ping-pong = 94.85 MB total (proven size)
    float* ws   = (float*)d_ws;
    float* feat = ws;                                     // (M,8)
    float* vbuf = feat + (size_t)M_SEQ * 8;               // (M,)
    int*   cbuf = (int*)(vbuf + M_SEQ);                   // (M,)
    float* bufA = (float*)(cbuf + M_SEQ);                 // (M,64,16)
    float* bufB = bufA + (size_t)M_SEQ * TT * 16;         // (M,64,16)

    const int ggru = (M_SEQ * 2 * 8) / 256;   // 720 blocks
    gru_fused<8><<<ggru, 256, 0, stream>>>(full_seq, g0wih, g0whh, g0bih, g0bhh, bufA);
    gru_fused<16><<<ggru, 256, 0, stream>>>(bufA, gwih + 0 * 768, gwhh + 0 * 384,
                                            gbih + 0 * 48, gbhh + 0 * 48, bufB);
    gru_fused<16><<<ggru, 256, 0, stream>>>(bufB, gwih + 1 * 768, gwhh + 1 * 384,
                                            gbih + 1 * 48, gbhh + 1 * 48, bufA);
    gru_fused<16><<<ggru, 256, 0, stream>>>(bufA, gwih + 2 * 768, gwhh + 2 * 384,
                                            gbih + 2 * 48, gbhh + 2 * 48, bufB);
    feat_kernel<<<M_SEQ / 256, 256, 0, stream>>>(bufB, l1w, l1b, l2w, l2b, feat);
    adj_kernel<<<(NB * NNODE) / 4, 256, 0, stream>>>(feat, temp, cbuf, vbuf);
    decode_kernel<<<NB, DTH, 0, stream>>>(rec_seq, cbuf, vbuf,
                                          enc_gw, enc_gb, enc_cw, enc_cb,
                                          dec_gw, dec_gb, dec_cw, dec_cb,
                                          proj_w, proj_b, outp);
}